// Round 14
// baseline (15220.985 us; speedup 1.0000x reference)
//
#include <hip/hip_runtime.h>

// ---------------------------------------------------------------------------
// PointNet++ (SSG) forward on MI355X.
// B=4, N=4096. sa1: S1=2048 r=0.2 K=64, MLP 6-64-64-128.
//              sa2: S2=512  r=0.4 K=64, MLP 131-128-128-256.
//              sa3: MLP 259-256-512-1024 + global max. fc: 1024->256.
// Discrete decisions (FPS argmax, radius membership, top-64 rank) are bitwise
// exact vs the f32 reference; __f*_rn blocks FMA contraction in d2.
// FPS argmax key = (f32bits<<32 | ~idx) built once per wave (r12-validated
// f32 DPP reduce + ballot/ctz/readlane). r14: winning lane publishes its
// COORDS next to the key (register select via compile-time unrolled chain --
// no dynamic reg indexing), post-barrier threads select winner coords by key
// compare: removes the second dependent LDS read (sx[cur]) from the serial
// chain. Keys are distinct across waves (disjoint index ranges).
// r13 REFUTED: 256-thr fps worse (per-wave issue on critical path) -- 512 thr.
// r4: v2f packed math regressed fps (scalarized) -- scalar only.
// r7/r8/r10: direct-global weights for mlp1/mlp2 (spill fix) validated.
// r9 REGRESSION: 512-thr rewritten mlp1 body spilled; keep 256-active body.
// Schedule: k1 fps[1,512) | k2 +nbr1Q1 | k3 +nbr1Q2+mlp1Q1 | k4 +nbr1Q3+
// mlp1Q2 | k5 fps2+nbr1Q4+mlp1Q3 | k6 nbr2+mlp1Q4 | mlp2 | gemms | mpfc.
// ---------------------------------------------------------------------------

#define DEVFN __device__ __forceinline__

DEVFN float d2_exact(float ax, float ay, float az, float bx, float by, float bz) {
    float dx = __fsub_rn(ax, bx);
    float dy = __fsub_rn(ay, by);
    float dz = __fsub_rn(az, bz);
    return __fadd_rn(__fadd_rn(__fmul_rn(dx, dx), __fmul_rn(dy, dy)), __fmul_rn(dz, dz));
}

DEVFN unsigned long long u64max(unsigned long long a, unsigned long long b) {
    return a > b ? a : b;
}

// DPP rotate-right by R within each 16-lane row, f32.
template <int R>
DEVFN float dpp_ror16_f32(float x) {
    int v = __builtin_amdgcn_update_dpp(__float_as_int(x), __float_as_int(x),
                                        0x120 | R, 0xF, 0xF, false);
    return __int_as_float(v);
}

DEVFN float rl_f32(float x, int lane) {
    return __int_as_float(__builtin_amdgcn_readlane(__float_as_int(x), lane));
}

// Per-wave argmax -> u64 key + winning lane (fl, uniform) + its slot (li,
// per-lane; valid on lane fl). Tie semantics identical to the u64-tree form.
template <int PPT>
DEVFN unsigned long long wave_argmax_key_fl(const float* mm, float mloc, int base,
                                            int& fl_out, int& li_out) {
    float w = mloc;
    w = fmaxf(w, dpp_ror16_f32<8>(w));
    w = fmaxf(w, dpp_ror16_f32<4>(w));
    w = fmaxf(w, dpp_ror16_f32<2>(w));
    w = fmaxf(w, dpp_ror16_f32<1>(w));   // each 16-lane row: row max
    float bw = fmaxf(fmaxf(rl_f32(w, 0), rl_f32(w, 16)),
                     fmaxf(rl_f32(w, 32), rl_f32(w, 48)));  // wave max, uniform
    int li = PPT - 1;
#pragma unroll
    for (int i = PPT - 2; i >= 0; --i) li = (mm[i] == bw) ? i : li;
    bool has = (mm[li] == bw);
    unsigned long long mask = __ballot(has);
    int fl = (int)__builtin_ctzll(mask);          // first lane = smallest idx
    int gi = __builtin_amdgcn_readlane(base + li, fl);
    fl_out = fl; li_out = li;
    return ((unsigned long long)__float_as_uint(bw) << 32) |
           (unsigned long long)(0xFFFFFFFFu - (unsigned)gi);
}

// Generic destructive fmax tree over a copy of md.
template <int PPT>
DEVFN float local_max(const float* md) {
    float mm[PPT];
#pragma unroll
    for (int i = 0; i < PPT; ++i) mm[i] = md[i];
#pragma unroll
    for (int w = PPT / 2; w >= 1; w >>= 1)
#pragma unroll
        for (int i = 0; i < w; ++i) mm[i] = fmaxf(mm[i], mm[i + w]);
    return mm[0];
}

// Compile-time-unrolled register select (avoids dynamic reg indexing).
template <int PPT>
DEVFN void select_coords(const float* px, const float* py, const float* pz,
                         int li, float& wx, float& wy, float& wz) {
    wx = px[0]; wy = py[0]; wz = pz[0];
#pragma unroll
    for (int i = 1; i < PPT; ++i) {
        bool e = (li == i);
        wx = e ? px[i] : wx; wy = e ? py[i] : wy; wz = e ? pz[i] : wz;
    }
}

// ---------------------------------------------------------------------------
// FPS core (stage 2), 512 threads, coords-exchange path (r14).
// ---------------------------------------------------------------------------
template <int N, int S, int NT>
DEVFN void run_fps(const float* sx, const float* sy, const float* sz,
                   unsigned long long* sPack,  // [2][NT/64]
                   float4* sCoord,             // [2][NT/64]
                   int* selLds) {
    constexpr int PPT = N / NT;
    constexpr int NW = NT / 64;
    const int tid = threadIdx.x;
    const int wv = tid >> 6;
    float px[PPT], py[PPT], pz[PPT], md[PPT];
#pragma unroll
    for (int i = 0; i < PPT; ++i) {
        int idx = tid * PPT + i;
        px[i] = sx[idx]; py[i] = sy[idx]; pz[i] = sz[idx];
        md[i] = __builtin_inff();
    }
    if (tid == 0) selLds[0] = 0;
    float ax = sx[0], ay = sy[0], az = sz[0];
    for (int s = 1; s < S; ++s) {
#pragma unroll
        for (int i = 0; i < PPT; ++i) {
            float d = d2_exact(px[i], py[i], pz[i], ax, ay, az);
            md[i] = fminf(md[i], d);
        }
        float mloc = local_max<PPT>(md);
        int fl, li;
        unsigned long long key = wave_argmax_key_fl<PPT>(md, mloc, tid * PPT, fl, li);

        const int par = (s & 1) * NW;
        if ((tid & 63) == 0) sPack[par + wv] = key;
        if ((tid & 63) == fl) {
            float wx, wy, wz;
            select_coords<PPT>(px, py, pz, li, wx, wy, wz);
            sCoord[par + wv] = make_float4(wx, wy, wz, 0.f);
        }
        __syncthreads();

        const ulonglong2* sp2 = (const ulonglong2*)(sPack + par);
        ulonglong2 q0 = sp2[0], q1 = sp2[1], q2 = sp2[2], q3 = sp2[3];
        float4 c0 = sCoord[par + 0], c1 = sCoord[par + 1];
        float4 c2 = sCoord[par + 2], c3 = sCoord[par + 3];
        float4 c4 = sCoord[par + 4], c5 = sCoord[par + 5];
        float4 c6 = sCoord[par + 6], c7 = sCoord[par + 7];
        unsigned long long m01 = u64max(u64max(q0.x, q0.y), u64max(q1.x, q1.y));
        unsigned long long m23 = u64max(u64max(q2.x, q2.y), u64max(q3.x, q3.y));
        unsigned long long win = u64max(m01, m23);

        float4 cc = c0;
        cc = (q0.y == win) ? c1 : cc;
        cc = (q1.x == win) ? c2 : cc;
        cc = (q1.y == win) ? c3 : cc;
        cc = (q2.x == win) ? c4 : cc;
        cc = (q2.y == win) ? c5 : cc;
        cc = (q3.x == win) ? c6 : cc;
        cc = (q3.y == win) ? c7 : cc;
        ax = cc.x; ay = cc.y; az = cc.z;

        if (tid == 0)
            selLds[s] = (int)(0xFFFFFFFFu - (unsigned)(win & 0xFFFFFFFFull));
    }
}

// ---------------------------------------------------------------------------
// Radius-neighbor body (r7-validated), one wave per center.
// ---------------------------------------------------------------------------
template <int N, int CAP>
DEVFN void nbr_body(const float* __restrict__ pos,
                    const float cx, const float cy, const float cz,
                    const float rsq, const int c,
                    int* __restrict__ nbr, int* __restrict__ cnt,
                    float* sDw, int* sIw) {
    const int lane = threadIdx.x & 63;
    int count = 0;
    for (int j = lane; j < N; j += 64) {
        float d = d2_exact(cx, cy, cz, pos[j * 3 + 0], pos[j * 3 + 1], pos[j * 3 + 2]);
        bool pred = (d <= rsq);
        unsigned long long m = __ballot(pred);
        int wpos = count + __popcll(m & ((1ull << lane) - 1ull));
        if (pred && wpos < CAP) { sDw[wpos] = d; sIw[wpos] = j; }
        count += __popcll(m);
    }
    if (count > CAP) count = CAP;

    for (int t = lane; t < count; t += 64) {
        float d = sDw[t]; int id = sIw[t];
        int rank = 0;
        int j0 = 0;
        for (; j0 + 4 <= count; j0 += 4) {
            float4 dj = *(const float4*)&sDw[j0];
            int4   ij = *(const int4*)&sIw[j0];
            rank += (dj.x < d || (dj.x == d && ij.x < id)) ? 1 : 0;
            rank += (dj.y < d || (dj.y == d && ij.y < id)) ? 1 : 0;
            rank += (dj.z < d || (dj.z == d && ij.z < id)) ? 1 : 0;
            rank += (dj.w < d || (dj.w == d && ij.w < id)) ? 1 : 0;
        }
        for (; j0 < count; ++j0) {
            float dj = sDw[j0]; int ij = sIw[j0];
            rank += (dj < d || (dj == d && ij < id)) ? 1 : 0;
        }
        if (rank < 64) nbr[(size_t)c * 64 + rank] = id;
    }
    if (lane == 0) cnt[c] = count < 64 ? count : 64;
}

// ---------------------------------------------------------------------------
// Register-tile FMA helpers (A from LDS; W from global; float4 rows)
// ---------------------------------------------------------------------------
DEVFN void tile44_fma(const float* __restrict__ aBase, int aStride,
                      const float* __restrict__ wBase, int wStride,
                      int nk4, float (&acc)[4][4]) {
    for (int k4 = 0; k4 < nk4; ++k4) {
        float a[4][4], w[4][4];
#pragma unroll
        for (int i = 0; i < 4; ++i) {
            float4 t = *(const float4*)(aBase + i * aStride + k4 * 4);
            a[i][0] = t.x; a[i][1] = t.y; a[i][2] = t.z; a[i][3] = t.w;
        }
#pragma unroll
        for (int kk = 0; kk < 4; ++kk) {
            float4 t = *(const float4*)(wBase + (size_t)(k4 * 4 + kk) * wStride);
            w[kk][0] = t.x; w[kk][1] = t.y; w[kk][2] = t.z; w[kk][3] = t.w;
        }
#pragma unroll
        for (int kk = 0; kk < 4; ++kk)
#pragma unroll
            for (int i = 0; i < 4; ++i)
#pragma unroll
                for (int j = 0; j < 4; ++j)
                    acc[i][j] = fmaf(a[i][kk], w[kk][j], acc[i][j]);
    }
}

DEVFN void tile48_fma(const float* __restrict__ aBase, int aStride,
                      const float* __restrict__ wBase, int wStride,
                      int nk4, float (&acc)[4][8]) {
    for (int k4 = 0; k4 < nk4; ++k4) {
        float a[4][4];
#pragma unroll
        for (int i = 0; i < 4; ++i) {
            float4 t = *(const float4*)(aBase + i * aStride + k4 * 4);
            a[i][0] = t.x; a[i][1] = t.y; a[i][2] = t.z; a[i][3] = t.w;
        }
#pragma unroll
        for (int kk = 0; kk < 4; ++kk) {
            float4 t0 = *(const float4*)(wBase + (size_t)(k4 * 4 + kk) * wStride);
            float4 t1 = *(const float4*)(wBase + (size_t)(k4 * 4 + kk) * wStride + 4);
            float w_[8] = {t0.x, t0.y, t0.z, t0.w, t1.x, t1.y, t1.z, t1.w};
#pragma unroll
            for (int i = 0; i < 4; ++i)
#pragma unroll
                for (int j = 0; j < 8; ++j)
                    acc[i][j] = fmaf(a[i][kk], w_[j], acc[i][j]);
        }
    }
}

// ---------------------------------------------------------------------------
// sa1 MLP body (r10-validated math), 256 ACTIVE threads; callable from
// 512-thread blocks: threads >= 256 idle but hit every barrier.
// ---------------------------------------------------------------------------
DEVFN void mlp1_body_guarded(const float* __restrict__ pos, const float* __restrict__ ctr,
                             const int* __restrict__ nbr, const int* __restrict__ cnt,
                             const float* __restrict__ w1, const float* __restrict__ b1,
                             const float* __restrict__ w2, const float* __restrict__ b2,
                             const float* __restrict__ w3, const float* __restrict__ b3,
                             float* __restrict__ x1, const int c, const int b,
                             float* smemf) {
    float* sFeat = smemf;           // [64][9]   (576)
    float* sH1   = smemf + 576;     // [64][68]  (4352)
    float* sH2   = smemf + 4928;    // [64][68]  (4352)
    float* sRed  = smemf + 9280;    // [16][128] (2048)
    const int tid = threadIdx.x;
    const int valid = cnt[c];

    if (tid < 64) {
        const int r = tid;
        float fx = 0.f, fy = 0.f, fz = 0.f, dx = 0.f, dy = 0.f, dz = 0.f;
        if (r < valid) {
            int j = nbr[(size_t)c * 64 + r];
            const float* pj = pos + ((size_t)b * 4096 + j) * 3;
            fx = pj[0]; fy = pj[1]; fz = pj[2];
            dx = fx - ctr[c * 3 + 0]; dy = fy - ctr[c * 3 + 1]; dz = fz - ctr[c * 3 + 2];
        }
        float* fr = sFeat + r * 9;
        fr[0] = fx; fr[1] = fy; fr[2] = fz; fr[3] = dx; fr[4] = dy; fr[5] = dz;
    }
    __syncthreads();

    if (tid < 256) {
        const int r = tid & 63, c0 = (tid >> 6) * 16;
        float acc[16];
#pragma unroll
        for (int q = 0; q < 16; ++q) acc[q] = b1[c0 + q];
#pragma unroll
        for (int k = 0; k < 6; ++k) {
            float a = sFeat[r * 9 + k];
#pragma unroll
            for (int q = 0; q < 16; ++q) acc[q] = fmaf(a, w1[k * 64 + c0 + q], acc[q]);
        }
        float* hr = sH1 + r * 68 + c0;
#pragma unroll
        for (int q = 0; q < 16; ++q) hr[q] = fmaxf(acc[q], 0.f);
    }
    __syncthreads();

    if (tid < 256) {
        const int r0 = (tid >> 4) * 4, c0 = (tid & 15) * 4;
        float acc[4][4];
#pragma unroll
        for (int i = 0; i < 4; ++i)
#pragma unroll
            for (int j = 0; j < 4; ++j) acc[i][j] = b2[c0 + j];
        tile44_fma(sH1 + r0 * 68, 68, w2 + c0, 64, 16, acc);
#pragma unroll
        for (int i = 0; i < 4; ++i)
#pragma unroll
            for (int j = 0; j < 4; ++j)
                sH2[(r0 + i) * 68 + c0 + j] = fmaxf(acc[i][j], 0.f);
    }
    __syncthreads();

    if (tid < 256) {
        const int r0 = (tid >> 4) * 4, c0 = (tid & 15) * 8;
        float acc[4][8];
#pragma unroll
        for (int i = 0; i < 4; ++i)
#pragma unroll
            for (int j = 0; j < 8; ++j) acc[i][j] = 0.f;
        tile48_fma(sH2 + r0 * 68, 68, w3 + c0, 128, 16, acc);
        float pm[8];
#pragma unroll
        for (int j = 0; j < 8; ++j) pm[j] = -__builtin_inff();
#pragma unroll
        for (int i = 0; i < 4; ++i)
            if (r0 + i < valid)
#pragma unroll
                for (int j = 0; j < 8; ++j) pm[j] = fmaxf(pm[j], acc[i][j]);
#pragma unroll
        for (int j = 0; j < 8; ++j) sRed[(tid >> 4) * 128 + c0 + j] = pm[j];
    }
    __syncthreads();
    if (tid < 128) {
        float m = -__builtin_inff();
#pragma unroll
        for (int g = 0; g < 16; ++g) m = fmaxf(m, sRed[g * 128 + tid]);
        x1[(size_t)c * 128 + tid] = m + b3[tid];
    }
}

// ---------------------------------------------------------------------------
// fpsnbr (512 thr): blocks 0..3 = fps stage-1 chunk [sb,se); 4..259 = nbr1
// quarter at s0n (8 centers/block); 260.. = mlp1 quarter at s0m.
// ---------------------------------------------------------------------------
__global__ __launch_bounds__(512) void fpsnbr_kernel(
    const float* __restrict__ data,   // [B][4096][3]
    float* __restrict__ mdG,          // [B][4096]
    int* __restrict__ selG,           // [B][2048]
    float* __restrict__ pos1,         // [B][2048][3]
    const int sb, const int se,
    const float rsq, int* __restrict__ nbr1, int* __restrict__ cnt1,
    const int s0n,
    const float* __restrict__ w1, const float* __restrict__ b1,
    const float* __restrict__ w2, const float* __restrict__ b2,
    const float* __restrict__ w3, const float* __restrict__ b3,
    float* __restrict__ x1, const int s0m)
{
    __shared__ __align__(16) char raw[65536];
    const int tid = threadIdx.x;

    if (blockIdx.x >= 260) {
        const int g = (int)blockIdx.x - 260;
        const int b = g >> 9;
        const int c = b * 2048 + s0m + (g & 511);
        mlp1_body_guarded(data, pos1, nbr1, cnt1, w1, b1, w2, b2, w3, b3,
                          x1, c, b, (float*)raw);
        return;
    }
    if (blockIdx.x >= 4) {
        float* sD = (float*)raw;                 // [8][1024]
        int*   sI = (int*)(raw + 32768);         // [8][1024]
        const int wid = tid >> 6;
        const int g = (int)(blockIdx.x - 4) * 8 + wid;   // [0, 2048)
        const int b = g >> 9;
        const int s = s0n + (g & 511);
        const int c = b * 2048 + s;
        const float cx = pos1[(size_t)c * 3 + 0];
        const float cy = pos1[(size_t)c * 3 + 1];
        const float cz = pos1[(size_t)c * 3 + 2];
        nbr_body<4096, 1024>(data + (size_t)b * 4096 * 3, cx, cy, cz, rsq, c,
                             nbr1, cnt1, sD + wid * 1024, sI + wid * 1024);
        return;
    }

    // ---- fps stage-1 chunk, 512 threads, coords-exchange path (r14) ----
    constexpr int N = 4096, NT = 512, PPT = N / NT, NW = NT / 64;
    float* sx = (float*)raw;
    float* sy = sx + 4096;
    float* sz = sy + 4096;
    unsigned long long* sPack = (unsigned long long*)(raw + 49152);  // [2][8]
    int* sSel = (int*)(raw + 49280);                                  // [512]
    float4* sCoord = (float4*)(raw + 51328);                          // [2][8]

    const int b = blockIdx.x;
    const int wv = tid >> 6;
    const float* p = data + (size_t)b * N * 3;
    for (int i = tid; i < N; i += NT) {
        sx[i] = p[i * 3 + 0]; sy[i] = p[i * 3 + 1]; sz[i] = p[i * 3 + 2];
    }
    __syncthreads();

    float px[PPT], py[PPT], pz[PPT], md[PPT];
    const bool first = (sb == 1);
#pragma unroll
    for (int i = 0; i < PPT; ++i) {
        int idx = tid * PPT + i;
        px[i] = sx[idx]; py[i] = sy[idx]; pz[i] = sz[idx];
        md[i] = first ? __builtin_inff() : mdG[(size_t)b * N + idx];
    }
    int cur = first ? 0 : selG[(size_t)b * 2048 + sb - 1];
    if (first && tid == 0) selG[(size_t)b * 2048] = 0;
    float ax = sx[cur], ay = sy[cur], az = sz[cur];

    for (int s = sb; s < se; ++s) {
#pragma unroll
        for (int i = 0; i < PPT; ++i) {
            float d = d2_exact(px[i], py[i], pz[i], ax, ay, az);
            md[i] = fminf(md[i], d);
        }
        float mloc = local_max<PPT>(md);
        int fl, li;
        unsigned long long key = wave_argmax_key_fl<PPT>(md, mloc, tid * PPT, fl, li);

        const int par = (s & 1) * NW;
        if ((tid & 63) == 0) sPack[par + wv] = key;
        if ((tid & 63) == fl) {
            float wx, wy, wz;
            select_coords<PPT>(px, py, pz, li, wx, wy, wz);
            sCoord[par + wv] = make_float4(wx, wy, wz, 0.f);
        }
        __syncthreads();

        const ulonglong2* sp2 = (const ulonglong2*)(sPack + par);
        ulonglong2 q0 = sp2[0], q1 = sp2[1], q2 = sp2[2], q3 = sp2[3];
        float4 c0 = sCoord[par + 0], c1 = sCoord[par + 1];
        float4 c2 = sCoord[par + 2], c3 = sCoord[par + 3];
        float4 c4 = sCoord[par + 4], c5 = sCoord[par + 5];
        float4 c6 = sCoord[par + 6], c7 = sCoord[par + 7];
        unsigned long long m01 = u64max(u64max(q0.x, q0.y), u64max(q1.x, q1.y));
        unsigned long long m23 = u64max(u64max(q2.x, q2.y), u64max(q3.x, q3.y));
        unsigned long long win = u64max(m01, m23);

        float4 cc = c0;
        cc = (q0.y == win) ? c1 : cc;
        cc = (q1.x == win) ? c2 : cc;
        cc = (q1.y == win) ? c3 : cc;
        cc = (q2.x == win) ? c4 : cc;
        cc = (q2.y == win) ? c5 : cc;
        cc = (q3.x == win) ? c6 : cc;
        cc = (q3.y == win) ? c7 : cc;
        ax = cc.x; ay = cc.y; az = cc.z;

        cur = (int)(0xFFFFFFFFu - (unsigned)(win & 0xFFFFFFFFull));
        if (tid == 0) sSel[s - sb] = cur;
    }
    __syncthreads();

    if (se < 2048) {
#pragma unroll
        for (int i = 0; i < PPT; ++i)
            mdG[(size_t)b * N + tid * PPT + i] = md[i];
    }
    if (tid == 0) selG[(size_t)b * 2048 + se - 1] = cur;

    float* p1 = pos1 + (size_t)b * 2048 * 3;
    const int sb0 = first ? 0 : sb;
    for (int s = sb0 + tid; s < se; s += NT) {
        int idx = (s == 0) ? 0 : sSel[s - sb];
        p1[s * 3 + 0] = sx[idx]; p1[s * 3 + 1] = sy[idx]; p1[s * 3 + 2] = sz[idx];
    }
}

// ---------------------------------------------------------------------------
// fps2nbr (512 thr): blocks 0..3 = fps stage 2; 4..259 = nbr1 Q4;
// 260.. = mlp1 Q3 riders.
// ---------------------------------------------------------------------------
__global__ __launch_bounds__(512) void fps2nbr_kernel(
    const float* __restrict__ data,
    const float* __restrict__ pos1,   // [B][2048][3]
    float* __restrict__ pos2,         // [B][512][3]
    const float rsq, int* __restrict__ nbr1, int* __restrict__ cnt1,
    const int s0n,
    const float* __restrict__ w1, const float* __restrict__ b1,
    const float* __restrict__ w2, const float* __restrict__ b2,
    const float* __restrict__ w3, const float* __restrict__ b3,
    float* __restrict__ x1, const int s0m)
{
    __shared__ __align__(16) char raw[65536];
    const int tid = threadIdx.x;

    if (blockIdx.x >= 260) {
        const int g = (int)blockIdx.x - 260;
        const int b = g >> 9;
        const int c = b * 2048 + s0m + (g & 511);
        mlp1_body_guarded(data, pos1, nbr1, cnt1, w1, b1, w2, b2, w3, b3,
                          x1, c, b, (float*)raw);
        return;
    }
    if (blockIdx.x >= 4) {
        float* sD = (float*)raw;
        int*   sI = (int*)(raw + 32768);
        const int wid = tid >> 6;
        const int g = (int)(blockIdx.x - 4) * 8 + wid;
        const int b = g >> 9;
        const int s = s0n + (g & 511);
        const int c = b * 2048 + s;
        const float cx = pos1[(size_t)c * 3 + 0];
        const float cy = pos1[(size_t)c * 3 + 1];
        const float cz = pos1[(size_t)c * 3 + 2];
        nbr_body<4096, 1024>(data + (size_t)b * 4096 * 3, cx, cy, cz, rsq, c,
                             nbr1, cnt1, sD + wid * 1024, sI + wid * 1024);
        return;
    }

    float* sx = (float*)raw;                              // [2048]
    float* sy = sx + 2048;
    float* sz = sy + 2048;
    int* sSel2 = (int*)(raw + 24576);                     // [512]
    unsigned long long* sPack2 = (unsigned long long*)(raw + 26624);  // [2][8]
    float4* sCoord2 = (float4*)(raw + 26752);                          // [2][8]

    const int b = blockIdx.x;
    const float* p1 = pos1 + (size_t)b * 2048 * 3;
    for (int i = tid; i < 2048; i += 512) {
        sx[i] = p1[i * 3 + 0]; sy[i] = p1[i * 3 + 1]; sz[i] = p1[i * 3 + 2];
    }
    __syncthreads();

    run_fps<2048, 512, 512>(sx, sy, sz, sPack2, sCoord2, sSel2);
    __syncthreads();

    float* p2 = pos2 + (size_t)b * 512 * 3;
    {
        int si = sSel2[tid];
        p2[tid * 3 + 0] = sx[si]; p2[tid * 3 + 1] = sy[si]; p2[tid * 3 + 2] = sz[si];
    }
}

// ---------------------------------------------------------------------------
// mlp1nbr2: blocks 0..511 = nbr2; blocks 512..2559 = mlp1 Q4.
// ---------------------------------------------------------------------------
__global__ __launch_bounds__(256) void mlp1nbr2_kernel(
    const float* __restrict__ pos,   // [B][4096][3]
    const float* __restrict__ ctr,   // [8192][3] = pos1
    const int* __restrict__ nbr, const int* __restrict__ cnt,
    const float* __restrict__ w1, const float* __restrict__ b1,
    const float* __restrict__ w2, const float* __restrict__ b2,
    const float* __restrict__ w3, const float* __restrict__ b3,
    float* __restrict__ x1,          // [8192][128]
    const float* __restrict__ pos1,  // [B][2048][3]
    const float* __restrict__ pos2,  // [B][512][3]
    const float rsq2, int* __restrict__ nbr2, int* __restrict__ cnt2,
    const int s0m)
{
    __shared__ __align__(16) float smem[12288];   // 48 KB
    const int tid = threadIdx.x;

    if (blockIdx.x < 512) {
        float* sD = smem;                        // [4][1536]
        int*   sI = (int*)(smem + 6144);         // [4][1536]
        const int wid = tid >> 6;
        const int c = (int)blockIdx.x * 4 + wid;  // [0, 2048)
        const int b = c >> 9;
        const float cx = pos2[(size_t)c * 3 + 0];
        const float cy = pos2[(size_t)c * 3 + 1];
        const float cz = pos2[(size_t)c * 3 + 2];
        nbr_body<2048, 1536>(pos1 + (size_t)b * 2048 * 3, cx, cy, cz, rsq2, c,
                             nbr2, cnt2, sD + wid * 1536, sI + wid * 1536);
        return;
    }

    const int g = (int)blockIdx.x - 512;
    const int b = g >> 9;
    const int c = b * 2048 + s0m + (g & 511);
    mlp1_body_guarded(pos, ctr, nbr, cnt, w1, b1, w2, b2, w3, b3,
                      x1, c, b, smem);
}

// ---------------------------------------------------------------------------
// sa2 MLP (r8-validated): direct-global weights, 4 barriers, LDS 67.6 KB.
// ---------------------------------------------------------------------------
__global__ __launch_bounds__(512, 4) void mlp2_kernel(
    const float* __restrict__ x1,    // [B*2048][128]
    const float* __restrict__ pos1,  // [B*2048][3]
    const float* __restrict__ ctr,   // [2048][3]
    const int* __restrict__ nbr, const int* __restrict__ cnt,
    const float* __restrict__ w1, const float* __restrict__ b1,
    const float* __restrict__ w2, const float* __restrict__ b2,
    const float* __restrict__ w3, const float* __restrict__ b3,
    float* __restrict__ x2)          // [2048][256]
{
    __shared__ __align__(16) float sF[64 * 132];   // feats, then h2
    __shared__ __align__(16) float sH[64 * 132];   // h1; sRed overlays after L2
    float* sRed = sH;                               // [16][256]

    const int tid = threadIdx.x;
    const int c = blockIdx.x;
    const int b = c >> 9;
    const int valid = cnt[c];
    const float cx = ctr[c * 3 + 0], cy = ctr[c * 3 + 1], cz = ctr[c * 3 + 2];

    {
        const int r = tid >> 3, t8 = tid & 7;
        float* fr = sF + r * 132;
        if (r < valid) {
            int j = nbr[(size_t)c * 64 + r];
            const float* xp = x1 + ((size_t)b * 2048 + j) * 128;
#pragma unroll
            for (int q = 0; q < 4; ++q) {
                float4 v = *(const float4*)(xp + t8 * 16 + q * 4);
                fr[t8 * 16 + q * 4 + 0] = v.x; fr[t8 * 16 + q * 4 + 1] = v.y;
                fr[t8 * 16 + q * 4 + 2] = v.z; fr[t8 * 16 + q * 4 + 3] = v.w;
            }
            if (t8 == 0) {
                const float* pj = pos1 + ((size_t)b * 2048 + j) * 3;
                fr[128] = pj[0] - cx; fr[129] = pj[1] - cy; fr[130] = pj[2] - cz;
                fr[131] = 0.f;
            }
        } else {
#pragma unroll
            for (int q = 0; q < 16; ++q) fr[t8 * 16 + q] = 0.f;
            if (t8 == 0) { fr[128] = 0.f; fr[129] = 0.f; fr[130] = 0.f; fr[131] = 0.f; }
        }
    }
    __syncthreads();

    const int r0 = (tid >> 5) * 4;        // 16 row-groups x 4 rows
    const int c0 = (tid & 31) * 4;        // l1/l2 cols
    const int c8 = (tid & 31) * 8;        // l3 cols

    {
        float acc[4][4];
#pragma unroll
        for (int i = 0; i < 4; ++i)
#pragma unroll
            for (int j = 0; j < 4; ++j) acc[i][j] = b1[c0 + j];
        tile44_fma(sF + r0 * 132, 132, w1 + c0, 128, 32, acc);
        for (int k = 128; k < 131; ++k) {
            float4 wv = *(const float4*)(w1 + (size_t)k * 128 + c0);
            float w_[4] = {wv.x, wv.y, wv.z, wv.w};
#pragma unroll
            for (int i = 0; i < 4; ++i) {
                float a = sF[(r0 + i) * 132 + k];
#pragma unroll
                for (int j = 0; j < 4; ++j) acc[i][j] = fmaf(a, w_[j], acc[i][j]);
            }
        }
#pragma unroll
        for (int i = 0; i < 4; ++i)
#pragma unroll
            for (int j = 0; j < 4; ++j)
                sH[(r0 + i) * 132 + c0 + j] = fmaxf(acc[i][j], 0.f);
    }
    __syncthreads();

    {
        float acc[4][4];
#pragma unroll
        for (int i = 0; i < 4; ++i)
#pragma unroll
            for (int j = 0; j < 4; ++j) acc[i][j] = b2[c0 + j];
        tile44_fma(sH + r0 * 132, 132, w2 + c0, 128, 32, acc);
#pragma unroll
        for (int i = 0; i < 4; ++i)
#pragma unroll
            for (int j = 0; j < 4; ++j)
                sF[(r0 + i) * 132 + c0 + j] = fmaxf(acc[i][j], 0.f);
    }
    __syncthreads();

    {
        float acc[4][8];
#pragma unroll
        for (int i = 0; i < 4; ++i)
#pragma unroll
            for (int j = 0; j < 8; ++j) acc[i][j] = 0.f;
        tile48_fma(sF + r0 * 132, 132, w3 + c8, 256, 32, acc);
        float pm[8];
#pragma unroll
        for (int j = 0; j < 8; ++j) pm[j] = -__builtin_inff();
#pragma unroll
        for (int i = 0; i < 4; ++i)
            if (r0 + i < valid)
#pragma unroll
                for (int j = 0; j < 8; ++j) pm[j] = fmaxf(pm[j], acc[i][j]);
#pragma unroll
        for (int j = 0; j < 8; ++j) sRed[(tid >> 5) * 256 + c8 + j] = pm[j];
    }
    __syncthreads();
    if (tid < 256) {
        float m = -__builtin_inff();
#pragma unroll
        for (int g = 0; g < 16; ++g) m = fmaxf(m, sRed[g * 256 + tid]);
        x2[(size_t)c * 256 + tid] = m + b3[tid];
    }
}

// ---------------------------------------------------------------------------
// gemm1f: A = cat([x2, pos2]) on the fly. K=259, relu.
// ---------------------------------------------------------------------------
__global__ __launch_bounds__(256) void gemm1f_kernel(const float* __restrict__ x2,
                                                     const float* __restrict__ pos2,
                                                     const float* __restrict__ W,
                                                     const float* __restrict__ bias,
                                                     float* __restrict__ C) {
    constexpr int K = 259, Nc = 256;
    __shared__ __align__(16) float sA[64 * 36];
    __shared__ __align__(16) float sB[32 * 68];
    const int tid = threadIdx.x;
    const int row0 = blockIdx.y * 64, col0 = blockIdx.x * 64;
    const int r0 = (tid >> 4) * 4, c0 = (tid & 15) * 4;
    float acc[4][4];
#pragma unroll
    for (int i = 0; i < 4; ++i)
#pragma unroll
        for (int j = 0; j < 4; ++j) acc[i][j] = 0.f;

    for (int kb = 0; kb < K; kb += 32) {
        for (int l = tid; l < 64 * 32; l += 256) {
            int r = l >> 5, k = l & 31;
            int gk = kb + k;
            float av = 0.f;
            if (gk < K) {
                int row = row0 + r;
                av = (gk < 256) ? x2[(size_t)row * 256 + gk]
                                : pos2[row * 3 + (gk - 256)];
            }
            sA[r * 36 + k] = av;
        }
        for (int l = tid; l < 32 * 64; l += 256) {
            int k = l >> 6, cc = l & 63;
            sB[k * 68 + cc] = (kb + k < K) ? W[(size_t)(kb + k) * Nc + col0 + cc] : 0.f;
        }
        __syncthreads();
        tile44_fma(sA + r0 * 36, 36, sB + c0, 68, 8, acc);
        __syncthreads();
    }
#pragma unroll
    for (int i = 0; i < 4; ++i)
#pragma unroll
        for (int j = 0; j < 4; ++j)
            C[(size_t)(row0 + r0 + i) * Nc + col0 + c0 + j] =
                fmaxf(acc[i][j] + bias[col0 + c0 + j], 0.f);
}

__global__ __launch_bounds__(256) void gemm_kernel(const float* __restrict__ A,
                                                   const float* __restrict__ W,
                                                   const float* __restrict__ bias,
                                                   float* __restrict__ C,
                                                   int M, int K, int Nc, int relu) {
    __shared__ __align__(16) float sA[64 * 36];
    __shared__ __align__(16) float sB[32 * 68];
    const int tid = threadIdx.x;
    const int row0 = blockIdx.y * 64, col0 = blockIdx.x * 64;
    const int r0 = (tid >> 4) * 4, c0 = (tid & 15) * 4;
    float acc[4][4];
#pragma unroll
    for (int i = 0; i < 4; ++i)
#pragma unroll
        for (int j = 0; j < 4; ++j) acc[i][j] = 0.f;

    for (int kb = 0; kb < K; kb += 32) {
        for (int l = tid; l < 64 * 32; l += 256) {
            int r = l >> 5, k = l & 31;
            sA[r * 36 + k] = (kb + k < K) ? A[(size_t)(row0 + r) * K + kb + k] : 0.f;
        }
        for (int l = tid; l < 32 * 64; l += 256) {
            int k = l >> 6, cc = l & 63;
            sB[k * 68 + cc] = (kb + k < K) ? W[(size_t)(kb + k) * Nc + col0 + cc] : 0.f;
        }
        __syncthreads();
        tile44_fma(sA + r0 * 36, 36, sB + c0, 68, 8, acc);
        __syncthreads();
    }
#pragma unroll
    for (int i = 0; i < 4; ++i)
#pragma unroll
        for (int j = 0; j < 4; ++j) {
            float v = acc[i][j] + bias[col0 + c0 + j];
            if (relu) v = fmaxf(v, 0.f);
            C[(size_t)(row0 + r0 + i) * Nc + col0 + c0 + j] = v;
        }
}

// ---------------------------------------------------------------------------
// maxpool over 512 rows + fc (1024->256), fused: one block per batch.
// ---------------------------------------------------------------------------
__global__ __launch_bounds__(1024) void mpfc_kernel(const float* __restrict__ h,
                                                    const float* __restrict__ w,
                                                    const float* __restrict__ bias,
                                                    float* __restrict__ out) {
    __shared__ float sG[1024];
    __shared__ float sP[4][256];
    const int b = blockIdx.x, tid = threadIdx.x;

    float m = -__builtin_inff();
    const float* hp = h + (size_t)b * 512 * 1024 + tid;
    for (int r = 0; r < 512; ++r) m = fmaxf(m, hp[(size_t)r * 1024]);
    sG[tid] = m;
    __syncthreads();

    const int c = tid & 255, kc = tid >> 8;
    float acc = 0.f;
    const float* wp = w + (size_t)(kc * 256) * 256 + c;
    const float* gp = sG + kc * 256;
    for (int k = 0; k < 256; ++k) acc = fmaf(gp[k], wp[(size_t)k * 256], acc);
    sP[kc][c] = acc;
    __syncthreads();
    if (tid < 256)
        out[b * 256 + tid] = ((sP[0][tid] + sP[1][tid]) + (sP[2][tid] + sP[3][tid]))
                             + bias[tid];
}

// ---------------------------------------------------------------------------
extern "C" void kernel_launch(void* const* d_in, const int* in_sizes, int n_in,
                              void* d_out, int out_size, void* d_ws, size_t ws_size,
                              hipStream_t stream) {
    const float* data  = (const float*)d_in[0];
    const float* s1w1  = (const float*)d_in[1];
    const float* s1b1  = (const float*)d_in[2];
    const float* s1w2  = (const float*)d_in[3];
    const float* s1b2  = (const float*)d_in[4];
    const float* s1w3  = (const float*)d_in[5];
    const float* s1b3  = (const float*)d_in[6];
    const float* s2w1  = (const float*)d_in[7];
    const float* s2b1  = (const float*)d_in[8];
    const float* s2w2  = (const float*)d_in[9];
    const float* s2b2  = (const float*)d_in[10];
    const float* s2w3  = (const float*)d_in[11];
    const float* s2b3  = (const float*)d_in[12];
    const float* s3w1  = (const float*)d_in[13];
    const float* s3b1  = (const float*)d_in[14];
    const float* s3w2  = (const float*)d_in[15];
    const float* s3b2  = (const float*)d_in[16];
    const float* s3w3  = (const float*)d_in[17];
    const float* s3b3  = (const float*)d_in[18];
    const float* fcw   = (const float*)d_in[19];
    const float* fcb   = (const float*)d_in[20];
    float* out = (float*)d_out;

    char* ws = (char*)d_ws;
    size_t o = 0;
    auto nxt = [&](size_t bytes) {
        size_t r = o;
        o += (bytes + 255) & ~(size_t)255;
        return r;
    };
    float* pos1 = (float*)(ws + nxt(4 * 2048 * 3 * 4));
    float* pos2 = (float*)(ws + nxt(4 * 512 * 3 * 4));
    float* mdG  = (float*)(ws + nxt(4 * 4096 * 4));
    int*   selG = (int*)(ws + nxt(4 * 2048 * 4));
    int*   nbr1 = (int*)(ws + nxt((size_t)8192 * 64 * 4));
    int*   cnt1 = (int*)(ws + nxt(8192 * 4));
    int*   nbr2 = (int*)(ws + nxt((size_t)2048 * 64 * 4));
    int*   cnt2 = (int*)(ws + nxt(2048 * 4));
    float* x1   = (float*)(ws + nxt((size_t)8192 * 128 * 4));
    float* x2   = (float*)(ws + nxt((size_t)2048 * 256 * 4));
    float* h1   = (float*)(ws + nxt((size_t)2048 * 256 * 4));
    float* h2   = (float*)(ws + nxt((size_t)2048 * 512 * 4));
    float* h3   = (float*)(ws + nxt((size_t)2048 * 1024 * 4));

    const float R1SQ = (float)(0.2 * 0.2);  // JAX weak-scalar f32 cast
    const float R2SQ = (float)(0.4 * 0.4);

    // k1: fps [1,512) alone
    fpsnbr_kernel<<<4, 512, 0, stream>>>(data, mdG, selG, pos1, 1, 512,
                                         R1SQ, nbr1, cnt1, 0,
                                         s1w1, s1b1, s1w2, s1b2, s1w3, s1b3, x1, 0);
    // k2: fps [512,1024) + nbr1 Q1
    fpsnbr_kernel<<<260, 512, 0, stream>>>(data, mdG, selG, pos1, 512, 1024,
                                           R1SQ, nbr1, cnt1, 0,
                                           s1w1, s1b1, s1w2, s1b2, s1w3, s1b3, x1, 0);
    // k3: fps [1024,1536) + nbr1 Q2 + mlp1 Q1
    fpsnbr_kernel<<<2308, 512, 0, stream>>>(data, mdG, selG, pos1, 1024, 1536,
                                            R1SQ, nbr1, cnt1, 512,
                                            s1w1, s1b1, s1w2, s1b2, s1w3, s1b3, x1, 0);
    // k4: fps [1536,2048) + nbr1 Q3 + mlp1 Q2
    fpsnbr_kernel<<<2308, 512, 0, stream>>>(data, mdG, selG, pos1, 1536, 2048,
                                            R1SQ, nbr1, cnt1, 1024,
                                            s1w1, s1b1, s1w2, s1b2, s1w3, s1b3, x1, 512);
    // k5: fps stage2 + nbr1 Q4 + mlp1 Q3
    fps2nbr_kernel<<<2308, 512, 0, stream>>>(data, pos1, pos2,
                                             R1SQ, nbr1, cnt1, 1536,
                                             s1w1, s1b1, s1w2, s1b2, s1w3, s1b3, x1, 1024);
    // k6: nbr2 + mlp1 Q4
    mlp1nbr2_kernel<<<2560, 256, 0, stream>>>(data, pos1, nbr1, cnt1,
                                              s1w1, s1b1, s1w2, s1b2,
                                              s1w3, s1b3, x1,
                                              pos1, pos2, R2SQ, nbr2, cnt2, 1536);
    mlp2_kernel<<<2048, 512, 0, stream>>>(x1, pos1, pos2, nbr2, cnt2,
                                          s2w1, s2b1, s2w2, s2b2, s2w3, s2b3, x2);
    gemm1f_kernel<<<dim3(4, 32), 256, 0, stream>>>(x2, pos2, s3w1, s3b1, h1);
    gemm_kernel<<<dim3(8, 32), 256, 0, stream>>>(h1, s3w2, s3b2, h2, 2048, 256, 512, 1);
    gemm_kernel<<<dim3(16, 32), 256, 0, stream>>>(h2, s3w3, s3b3, h3, 2048, 512, 1024, 0);
    mpfc_kernel<<<4, 1024, 0, stream>>>(h3, fcw, fcb, out);
}

// Round 15
// 2424.880 us; speedup vs baseline: 6.2770x; 6.2770x over previous
//
#include <hip/hip_runtime.h>

// ---------------------------------------------------------------------------
// PointNet++ (SSG) forward on MI355X.
// B=4, N=4096. sa1: S1=2048 r=0.2 K=64, MLP 6-64-64-128.
//              sa2: S2=512  r=0.4 K=64, MLP 131-128-128-256.
//              sa3: MLP 259-256-512-1024 + global max. fc: 1024->256.
// Discrete decisions (FPS argmax, radius membership, top-64 rank) are bitwise
// exact vs the f32 reference; __f*_rn blocks FMA contraction in d2.
// FPS argmax key = (f32bits<<32 | ~idx) built once per wave; wave-internal
// argmax via f32 fmax DPP reduce + ballot/ctz/readlane (r12-validated).
// r14 REVERTED: coords-exchange (divergent-lane float4 LDS store on the
// serial chain) stalled fps 8x -- divergent LDS stores are poison there.
// r13 REFUTED: 256-thr fps worse (per-wave issue on critical path).
// r4: v2f packed math regressed fps (scalarized) -- scalar only.
// r7/r8/r10: direct-global weights for mlp1/mlp2 (spill fix) validated.
// r9 REGRESSION: 512-thr rewritten mlp1 body spilled; keep 256-active body.
// This is the r12 configuration (best known: 2429 us).
// Schedule: k1 fps[1,512) | k2 +nbr1Q1 | k3 +nbr1Q2+mlp1Q1 | k4 +nbr1Q3+
// mlp1Q2 | k5 fps2+nbr1Q4+mlp1Q3 | k6 nbr2+mlp1Q4 | mlp2 | gemms | mpfc.
// ---------------------------------------------------------------------------

#define DEVFN __device__ __forceinline__

DEVFN float d2_exact(float ax, float ay, float az, float bx, float by, float bz) {
    float dx = __fsub_rn(ax, bx);
    float dy = __fsub_rn(ay, by);
    float dz = __fsub_rn(az, bz);
    return __fadd_rn(__fadd_rn(__fmul_rn(dx, dx), __fmul_rn(dy, dy)), __fmul_rn(dz, dz));
}

DEVFN unsigned long long u64max(unsigned long long a, unsigned long long b) {
    return a > b ? a : b;
}

// DPP rotate-right by R within each 16-lane row, f32.
template <int R>
DEVFN float dpp_ror16_f32(float x) {
    int v = __builtin_amdgcn_update_dpp(__float_as_int(x), __float_as_int(x),
                                        0x120 | R, 0xF, 0xF, false);
    return __int_as_float(v);
}

DEVFN float rl_f32(float x, int lane) {
    return __int_as_float(__builtin_amdgcn_readlane(__float_as_int(x), lane));
}

// Per-wave argmax -> u64 key. mm[PPT] = lane's values, base = lane's first
// global index. Returns (wavemax<<32 | ~gidx), gidx = smallest global index
// among wave-maximal values (bitwise-identical tie semantics to u64 tree).
template <int PPT>
DEVFN unsigned long long wave_argmax_key(const float* mm, float mloc, int base) {
    float w = mloc;
    w = fmaxf(w, dpp_ror16_f32<8>(w));
    w = fmaxf(w, dpp_ror16_f32<4>(w));
    w = fmaxf(w, dpp_ror16_f32<2>(w));
    w = fmaxf(w, dpp_ror16_f32<1>(w));   // each 16-lane row: row max
    float bw = fmaxf(fmaxf(rl_f32(w, 0), rl_f32(w, 16)),
                     fmaxf(rl_f32(w, 32), rl_f32(w, 48)));  // wave max, uniform
    int li = PPT - 1;
#pragma unroll
    for (int i = PPT - 2; i >= 0; --i) li = (mm[i] == bw) ? i : li;
    bool has = (mm[li] == bw);
    unsigned long long mask = __ballot(has);
    int fl = (int)__builtin_ctzll(mask);          // first lane = smallest idx
    int gi = __builtin_amdgcn_readlane(base + li, fl);
    return ((unsigned long long)__float_as_uint(bw) << 32) |
           (unsigned long long)(0xFFFFFFFFu - (unsigned)gi);
}

// ---------------------------------------------------------------------------
// FPS core (stage 2), 512 threads, f32-reduce path (r12).
// ---------------------------------------------------------------------------
template <int N, int S, int NT>
DEVFN void run_fps(const float* sx, const float* sy, const float* sz,
                   unsigned long long* sPack,  // [2][NT/64]
                   int* selLds) {
    constexpr int PPT = N / NT;
    constexpr int NW = NT / 64;
    const int tid = threadIdx.x;
    float px[PPT], py[PPT], pz[PPT], md[PPT];
#pragma unroll
    for (int i = 0; i < PPT; ++i) {
        int idx = tid * PPT + i;
        px[i] = sx[idx]; py[i] = sy[idx]; pz[i] = sz[idx];
        md[i] = __builtin_inff();
    }
    if (tid == 0) selLds[0] = 0;
    int cur = 0;
    for (int s = 1; s < S; ++s) {
        float ax = sx[cur], ay = sy[cur], az = sz[cur];
#pragma unroll
        for (int i = 0; i < PPT; ++i) {
            float d = d2_exact(px[i], py[i], pz[i], ax, ay, az);
            md[i] = fminf(md[i], d);
        }
        float t0 = fmaxf(md[0], md[1]), t1 = fmaxf(md[2], md[3]);
        float mloc = fmaxf(t0, t1);   // PPT == 4
        unsigned long long key = wave_argmax_key<PPT>(md, mloc, tid * PPT);

        unsigned long long* sp = sPack + (s & 1) * NW;
        if ((tid & 63) == 0) sp[tid >> 6] = key;
        __syncthreads();

        const ulonglong2* sp2 = (const ulonglong2*)sp;
        ulonglong2 q0 = sp2[0], q1 = sp2[1], q2 = sp2[2], q3 = sp2[3];
        unsigned long long m01 = u64max(u64max(q0.x, q0.y), u64max(q1.x, q1.y));
        unsigned long long m23 = u64max(u64max(q2.x, q2.y), u64max(q3.x, q3.y));
        unsigned long long win = u64max(m01, m23);

        cur = (int)(0xFFFFFFFFu - (unsigned)(win & 0xFFFFFFFFull));
        if (tid == 0) selLds[s] = cur;
    }
}

// ---------------------------------------------------------------------------
// Radius-neighbor body (r7-validated), one wave per center.
// ---------------------------------------------------------------------------
template <int N, int CAP>
DEVFN void nbr_body(const float* __restrict__ pos,
                    const float cx, const float cy, const float cz,
                    const float rsq, const int c,
                    int* __restrict__ nbr, int* __restrict__ cnt,
                    float* sDw, int* sIw) {
    const int lane = threadIdx.x & 63;
    int count = 0;
    for (int j = lane; j < N; j += 64) {
        float d = d2_exact(cx, cy, cz, pos[j * 3 + 0], pos[j * 3 + 1], pos[j * 3 + 2]);
        bool pred = (d <= rsq);
        unsigned long long m = __ballot(pred);
        int wpos = count + __popcll(m & ((1ull << lane) - 1ull));
        if (pred && wpos < CAP) { sDw[wpos] = d; sIw[wpos] = j; }
        count += __popcll(m);
    }
    if (count > CAP) count = CAP;

    for (int t = lane; t < count; t += 64) {
        float d = sDw[t]; int id = sIw[t];
        int rank = 0;
        int j0 = 0;
        for (; j0 + 4 <= count; j0 += 4) {
            float4 dj = *(const float4*)&sDw[j0];
            int4   ij = *(const int4*)&sIw[j0];
            rank += (dj.x < d || (dj.x == d && ij.x < id)) ? 1 : 0;
            rank += (dj.y < d || (dj.y == d && ij.y < id)) ? 1 : 0;
            rank += (dj.z < d || (dj.z == d && ij.z < id)) ? 1 : 0;
            rank += (dj.w < d || (dj.w == d && ij.w < id)) ? 1 : 0;
        }
        for (; j0 < count; ++j0) {
            float dj = sDw[j0]; int ij = sIw[j0];
            rank += (dj < d || (dj == d && ij < id)) ? 1 : 0;
        }
        if (rank < 64) nbr[(size_t)c * 64 + rank] = id;
    }
    if (lane == 0) cnt[c] = count < 64 ? count : 64;
}

// ---------------------------------------------------------------------------
// Register-tile FMA helpers (A from LDS; W from global; float4 rows)
// ---------------------------------------------------------------------------
DEVFN void tile44_fma(const float* __restrict__ aBase, int aStride,
                      const float* __restrict__ wBase, int wStride,
                      int nk4, float (&acc)[4][4]) {
    for (int k4 = 0; k4 < nk4; ++k4) {
        float a[4][4], w[4][4];
#pragma unroll
        for (int i = 0; i < 4; ++i) {
            float4 t = *(const float4*)(aBase + i * aStride + k4 * 4);
            a[i][0] = t.x; a[i][1] = t.y; a[i][2] = t.z; a[i][3] = t.w;
        }
#pragma unroll
        for (int kk = 0; kk < 4; ++kk) {
            float4 t = *(const float4*)(wBase + (size_t)(k4 * 4 + kk) * wStride);
            w[kk][0] = t.x; w[kk][1] = t.y; w[kk][2] = t.z; w[kk][3] = t.w;
        }
#pragma unroll
        for (int kk = 0; kk < 4; ++kk)
#pragma unroll
            for (int i = 0; i < 4; ++i)
#pragma unroll
                for (int j = 0; j < 4; ++j)
                    acc[i][j] = fmaf(a[i][kk], w[kk][j], acc[i][j]);
    }
}

DEVFN void tile48_fma(const float* __restrict__ aBase, int aStride,
                      const float* __restrict__ wBase, int wStride,
                      int nk4, float (&acc)[4][8]) {
    for (int k4 = 0; k4 < nk4; ++k4) {
        float a[4][4];
#pragma unroll
        for (int i = 0; i < 4; ++i) {
            float4 t = *(const float4*)(aBase + i * aStride + k4 * 4);
            a[i][0] = t.x; a[i][1] = t.y; a[i][2] = t.z; a[i][3] = t.w;
        }
#pragma unroll
        for (int kk = 0; kk < 4; ++kk) {
            float4 t0 = *(const float4*)(wBase + (size_t)(k4 * 4 + kk) * wStride);
            float4 t1 = *(const float4*)(wBase + (size_t)(k4 * 4 + kk) * wStride + 4);
            float w_[8] = {t0.x, t0.y, t0.z, t0.w, t1.x, t1.y, t1.z, t1.w};
#pragma unroll
            for (int i = 0; i < 4; ++i)
#pragma unroll
                for (int j = 0; j < 8; ++j)
                    acc[i][j] = fmaf(a[i][kk], w_[j], acc[i][j]);
        }
    }
}

// ---------------------------------------------------------------------------
// sa1 MLP body (r10-validated math), 256 ACTIVE threads.
// ---------------------------------------------------------------------------
DEVFN void mlp1_body_guarded(const float* __restrict__ pos, const float* __restrict__ ctr,
                             const int* __restrict__ nbr, const int* __restrict__ cnt,
                             const float* __restrict__ w1, const float* __restrict__ b1,
                             const float* __restrict__ w2, const float* __restrict__ b2,
                             const float* __restrict__ w3, const float* __restrict__ b3,
                             float* __restrict__ x1, const int c, const int b,
                             float* smemf) {
    float* sFeat = smemf;           // [64][9]   (576)
    float* sH1   = smemf + 576;     // [64][68]  (4352)
    float* sH2   = smemf + 4928;    // [64][68]  (4352)
    float* sRed  = smemf + 9280;    // [16][128] (2048)
    const int tid = threadIdx.x;
    const int valid = cnt[c];

    if (tid < 64) {
        const int r = tid;
        float fx = 0.f, fy = 0.f, fz = 0.f, dx = 0.f, dy = 0.f, dz = 0.f;
        if (r < valid) {
            int j = nbr[(size_t)c * 64 + r];
            const float* pj = pos + ((size_t)b * 4096 + j) * 3;
            fx = pj[0]; fy = pj[1]; fz = pj[2];
            dx = fx - ctr[c * 3 + 0]; dy = fy - ctr[c * 3 + 1]; dz = fz - ctr[c * 3 + 2];
        }
        float* fr = sFeat + r * 9;
        fr[0] = fx; fr[1] = fy; fr[2] = fz; fr[3] = dx; fr[4] = dy; fr[5] = dz;
    }
    __syncthreads();

    if (tid < 256) {
        const int r = tid & 63, c0 = (tid >> 6) * 16;
        float acc[16];
#pragma unroll
        for (int q = 0; q < 16; ++q) acc[q] = b1[c0 + q];
#pragma unroll
        for (int k = 0; k < 6; ++k) {
            float a = sFeat[r * 9 + k];
#pragma unroll
            for (int q = 0; q < 16; ++q) acc[q] = fmaf(a, w1[k * 64 + c0 + q], acc[q]);
        }
        float* hr = sH1 + r * 68 + c0;
#pragma unroll
        for (int q = 0; q < 16; ++q) hr[q] = fmaxf(acc[q], 0.f);
    }
    __syncthreads();

    if (tid < 256) {
        const int r0 = (tid >> 4) * 4, c0 = (tid & 15) * 4;
        float acc[4][4];
#pragma unroll
        for (int i = 0; i < 4; ++i)
#pragma unroll
            for (int j = 0; j < 4; ++j) acc[i][j] = b2[c0 + j];
        tile44_fma(sH1 + r0 * 68, 68, w2 + c0, 64, 16, acc);
#pragma unroll
        for (int i = 0; i < 4; ++i)
#pragma unroll
            for (int j = 0; j < 4; ++j)
                sH2[(r0 + i) * 68 + c0 + j] = fmaxf(acc[i][j], 0.f);
    }
    __syncthreads();

    if (tid < 256) {
        const int r0 = (tid >> 4) * 4, c0 = (tid & 15) * 8;
        float acc[4][8];
#pragma unroll
        for (int i = 0; i < 4; ++i)
#pragma unroll
            for (int j = 0; j < 8; ++j) acc[i][j] = 0.f;
        tile48_fma(sH2 + r0 * 68, 68, w3 + c0, 128, 16, acc);
        float pm[8];
#pragma unroll
        for (int j = 0; j < 8; ++j) pm[j] = -__builtin_inff();
#pragma unroll
        for (int i = 0; i < 4; ++i)
            if (r0 + i < valid)
#pragma unroll
                for (int j = 0; j < 8; ++j) pm[j] = fmaxf(pm[j], acc[i][j]);
#pragma unroll
        for (int j = 0; j < 8; ++j) sRed[(tid >> 4) * 128 + c0 + j] = pm[j];
    }
    __syncthreads();
    if (tid < 128) {
        float m = -__builtin_inff();
#pragma unroll
        for (int g = 0; g < 16; ++g) m = fmaxf(m, sRed[g * 128 + tid]);
        x1[(size_t)c * 128 + tid] = m + b3[tid];
    }
}

// ---------------------------------------------------------------------------
// fpsnbr: blocks 0..3 = fps stage-1 chunk [sb,se); 4..259 = nbr1 quarter at
// s0n; 260.. = mlp1 quarter at s0m (riders in the fps shadow).
// ---------------------------------------------------------------------------
__global__ __launch_bounds__(512) void fpsnbr_kernel(
    const float* __restrict__ data,   // [B][4096][3]
    float* __restrict__ mdG,          // [B][4096]
    int* __restrict__ selG,           // [B][2048]
    float* __restrict__ pos1,         // [B][2048][3]
    const int sb, const int se,
    const float rsq, int* __restrict__ nbr1, int* __restrict__ cnt1,
    const int s0n,
    const float* __restrict__ w1, const float* __restrict__ b1,
    const float* __restrict__ w2, const float* __restrict__ b2,
    const float* __restrict__ w3, const float* __restrict__ b3,
    float* __restrict__ x1, const int s0m)
{
    __shared__ __align__(16) char raw[65536];
    const int tid = threadIdx.x;

    if (blockIdx.x >= 260) {
        const int g = (int)blockIdx.x - 260;
        const int b = g >> 9;
        const int c = b * 2048 + s0m + (g & 511);
        mlp1_body_guarded(data, pos1, nbr1, cnt1, w1, b1, w2, b2, w3, b3,
                          x1, c, b, (float*)raw);
        return;
    }
    if (blockIdx.x >= 4) {
        float* sD = (float*)raw;                 // [8][1024]
        int*   sI = (int*)(raw + 32768);         // [8][1024]
        const int wid = tid >> 6;
        const int g = (int)(blockIdx.x - 4) * 8 + wid;   // [0, 2048)
        const int b = g >> 9;
        const int s = s0n + (g & 511);
        const int c = b * 2048 + s;
        const float cx = pos1[(size_t)c * 3 + 0];
        const float cy = pos1[(size_t)c * 3 + 1];
        const float cz = pos1[(size_t)c * 3 + 2];
        nbr_body<4096, 1024>(data + (size_t)b * 4096 * 3, cx, cy, cz, rsq, c,
                             nbr1, cnt1, sD + wid * 1024, sI + wid * 1024);
        return;
    }

    // ---- fps stage-1 chunk (f32-reduce path, r12) ----
    constexpr int N = 4096, NT = 512, PPT = N / NT, NW = NT / 64;
    float* sx = (float*)raw;
    float* sy = sx + 4096;
    float* sz = sy + 4096;
    unsigned long long* sPack = (unsigned long long*)(raw + 49152);  // [2][8]
    int* sSel = (int*)(raw + 49280);                                  // [512]

    const int b = blockIdx.x;
    const float* p = data + (size_t)b * N * 3;
    for (int i = tid; i < N; i += NT) {
        sx[i] = p[i * 3 + 0]; sy[i] = p[i * 3 + 1]; sz[i] = p[i * 3 + 2];
    }
    __syncthreads();

    float px[PPT], py[PPT], pz[PPT], md[PPT];
    const bool first = (sb == 1);
#pragma unroll
    for (int i = 0; i < PPT; ++i) {
        int idx = tid * PPT + i;
        px[i] = sx[idx]; py[i] = sy[idx]; pz[i] = sz[idx];
        md[i] = first ? __builtin_inff() : mdG[(size_t)b * N + idx];
    }
    int cur = first ? 0 : selG[(size_t)b * 2048 + sb - 1];
    if (first && tid == 0) selG[(size_t)b * 2048] = 0;

    for (int s = sb; s < se; ++s) {
        float ax = sx[cur], ay = sy[cur], az = sz[cur];
#pragma unroll
        for (int i = 0; i < PPT; ++i) {
            float d = d2_exact(px[i], py[i], pz[i], ax, ay, az);
            md[i] = fminf(md[i], d);
        }
        float a0 = fmaxf(md[0], md[4]), a1 = fmaxf(md[1], md[5]);
        float a2 = fmaxf(md[2], md[6]), a3 = fmaxf(md[3], md[7]);
        float b0 = fmaxf(a0, a2), b1 = fmaxf(a1, a3);
        float mloc = fmaxf(b0, b1);
        unsigned long long key = wave_argmax_key<PPT>(md, mloc, tid * PPT);

        unsigned long long* sp = sPack + (s & 1) * NW;
        if ((tid & 63) == 0) sp[tid >> 6] = key;
        __syncthreads();

        const ulonglong2* sp2 = (const ulonglong2*)sp;
        ulonglong2 q0 = sp2[0], q1 = sp2[1], q2 = sp2[2], q3 = sp2[3];
        unsigned long long m01 = u64max(u64max(q0.x, q0.y), u64max(q1.x, q1.y));
        unsigned long long m23 = u64max(u64max(q2.x, q2.y), u64max(q3.x, q3.y));
        unsigned long long win = u64max(m01, m23);

        cur = (int)(0xFFFFFFFFu - (unsigned)(win & 0xFFFFFFFFull));
        if (tid == 0) sSel[s - sb] = cur;
    }
    __syncthreads();

    if (se < 2048) {
#pragma unroll
        for (int i = 0; i < PPT; ++i)
            mdG[(size_t)b * N + tid * PPT + i] = md[i];
    }
    if (tid == 0) selG[(size_t)b * 2048 + se - 1] = cur;

    float* p1 = pos1 + (size_t)b * 2048 * 3;
    const int sb0 = first ? 0 : sb;
    for (int s = sb0 + tid; s < se; s += NT) {
        int idx = (s == 0) ? 0 : sSel[s - sb];
        p1[s * 3 + 0] = sx[idx]; p1[s * 3 + 1] = sy[idx]; p1[s * 3 + 2] = sz[idx];
    }
}

// ---------------------------------------------------------------------------
// fps2nbr: blocks 0..3 = fps stage 2 (pos1 -> pos2); 4..259 = nbr1 Q4;
// 260.. = mlp1 Q3 riders.
// ---------------------------------------------------------------------------
__global__ __launch_bounds__(512) void fps2nbr_kernel(
    const float* __restrict__ data,
    const float* __restrict__ pos1,   // [B][2048][3]
    float* __restrict__ pos2,         // [B][512][3]
    const float rsq, int* __restrict__ nbr1, int* __restrict__ cnt1,
    const int s0n,
    const float* __restrict__ w1, const float* __restrict__ b1,
    const float* __restrict__ w2, const float* __restrict__ b2,
    const float* __restrict__ w3, const float* __restrict__ b3,
    float* __restrict__ x1, const int s0m)
{
    __shared__ __align__(16) char raw[65536];
    const int tid = threadIdx.x;

    if (blockIdx.x >= 260) {
        const int g = (int)blockIdx.x - 260;
        const int b = g >> 9;
        const int c = b * 2048 + s0m + (g & 511);
        mlp1_body_guarded(data, pos1, nbr1, cnt1, w1, b1, w2, b2, w3, b3,
                          x1, c, b, (float*)raw);
        return;
    }
    if (blockIdx.x >= 4) {
        float* sD = (float*)raw;
        int*   sI = (int*)(raw + 32768);
        const int wid = tid >> 6;
        const int g = (int)(blockIdx.x - 4) * 8 + wid;
        const int b = g >> 9;
        const int s = s0n + (g & 511);
        const int c = b * 2048 + s;
        const float cx = pos1[(size_t)c * 3 + 0];
        const float cy = pos1[(size_t)c * 3 + 1];
        const float cz = pos1[(size_t)c * 3 + 2];
        nbr_body<4096, 1024>(data + (size_t)b * 4096 * 3, cx, cy, cz, rsq, c,
                             nbr1, cnt1, sD + wid * 1024, sI + wid * 1024);
        return;
    }

    float* sx = (float*)raw;                              // [2048]
    float* sy = sx + 2048;
    float* sz = sy + 2048;
    int* sSel2 = (int*)(raw + 24576);                     // [512]
    unsigned long long* sPack2 = (unsigned long long*)(raw + 26624);  // [2][8]

    const int b = blockIdx.x;
    const float* p1 = pos1 + (size_t)b * 2048 * 3;
    for (int i = tid; i < 2048; i += 512) {
        sx[i] = p1[i * 3 + 0]; sy[i] = p1[i * 3 + 1]; sz[i] = p1[i * 3 + 2];
    }
    __syncthreads();

    run_fps<2048, 512, 512>(sx, sy, sz, sPack2, sSel2);
    __syncthreads();

    float* p2 = pos2 + (size_t)b * 512 * 3;
    {
        int si = sSel2[tid];
        p2[tid * 3 + 0] = sx[si]; p2[tid * 3 + 1] = sy[si]; p2[tid * 3 + 2] = sz[si];
    }
}

// ---------------------------------------------------------------------------
// mlp1nbr2: blocks 0..511 = nbr2; blocks 512..2559 = mlp1 Q4.
// ---------------------------------------------------------------------------
__global__ __launch_bounds__(256) void mlp1nbr2_kernel(
    const float* __restrict__ pos,   // [B][4096][3]
    const float* __restrict__ ctr,   // [8192][3] = pos1
    const int* __restrict__ nbr, const int* __restrict__ cnt,
    const float* __restrict__ w1, const float* __restrict__ b1,
    const float* __restrict__ w2, const float* __restrict__ b2,
    const float* __restrict__ w3, const float* __restrict__ b3,
    float* __restrict__ x1,          // [8192][128]
    const float* __restrict__ pos1,  // [B][2048][3]
    const float* __restrict__ pos2,  // [B][512][3]
    const float rsq2, int* __restrict__ nbr2, int* __restrict__ cnt2,
    const int s0m)
{
    __shared__ __align__(16) float smem[12288];   // 48 KB
    const int tid = threadIdx.x;

    if (blockIdx.x < 512) {
        float* sD = smem;                        // [4][1536]
        int*   sI = (int*)(smem + 6144);         // [4][1536]
        const int wid = tid >> 6;
        const int c = (int)blockIdx.x * 4 + wid;  // [0, 2048)
        const int b = c >> 9;
        const float cx = pos2[(size_t)c * 3 + 0];
        const float cy = pos2[(size_t)c * 3 + 1];
        const float cz = pos2[(size_t)c * 3 + 2];
        nbr_body<2048, 1536>(pos1 + (size_t)b * 2048 * 3, cx, cy, cz, rsq2, c,
                             nbr2, cnt2, sD + wid * 1536, sI + wid * 1536);
        return;
    }

    const int g = (int)blockIdx.x - 512;
    const int b = g >> 9;
    const int c = b * 2048 + s0m + (g & 511);
    mlp1_body_guarded(pos, ctr, nbr, cnt, w1, b1, w2, b2, w3, b3,
                      x1, c, b, smem);
}

// ---------------------------------------------------------------------------
// sa2 MLP (r8-validated): direct-global weights, 4 barriers, LDS 67.6 KB.
// ---------------------------------------------------------------------------
__global__ __launch_bounds__(512, 4) void mlp2_kernel(
    const float* __restrict__ x1,    // [B*2048][128]
    const float* __restrict__ pos1,  // [B*2048][3]
    const float* __restrict__ ctr,   // [2048][3]
    const int* __restrict__ nbr, const int* __restrict__ cnt,
    const float* __restrict__ w1, const float* __restrict__ b1,
    const float* __restrict__ w2, const float* __restrict__ b2,
    const float* __restrict__ w3, const float* __restrict__ b3,
    float* __restrict__ x2)          // [2048][256]
{
    __shared__ __align__(16) float sF[64 * 132];   // feats, then h2
    __shared__ __align__(16) float sH[64 * 132];   // h1; sRed overlays after L2
    float* sRed = sH;                               // [16][256]

    const int tid = threadIdx.x;
    const int c = blockIdx.x;
    const int b = c >> 9;
    const int valid = cnt[c];
    const float cx = ctr[c * 3 + 0], cy = ctr[c * 3 + 1], cz = ctr[c * 3 + 2];

    {
        const int r = tid >> 3, t8 = tid & 7;
        float* fr = sF + r * 132;
        if (r < valid) {
            int j = nbr[(size_t)c * 64 + r];
            const float* xp = x1 + ((size_t)b * 2048 + j) * 128;
#pragma unroll
            for (int q = 0; q < 4; ++q) {
                float4 v = *(const float4*)(xp + t8 * 16 + q * 4);
                fr[t8 * 16 + q * 4 + 0] = v.x; fr[t8 * 16 + q * 4 + 1] = v.y;
                fr[t8 * 16 + q * 4 + 2] = v.z; fr[t8 * 16 + q * 4 + 3] = v.w;
            }
            if (t8 == 0) {
                const float* pj = pos1 + ((size_t)b * 2048 + j) * 3;
                fr[128] = pj[0] - cx; fr[129] = pj[1] - cy; fr[130] = pj[2] - cz;
                fr[131] = 0.f;
            }
        } else {
#pragma unroll
            for (int q = 0; q < 16; ++q) fr[t8 * 16 + q] = 0.f;
            if (t8 == 0) { fr[128] = 0.f; fr[129] = 0.f; fr[130] = 0.f; fr[131] = 0.f; }
        }
    }
    __syncthreads();

    const int r0 = (tid >> 5) * 4;        // 16 row-groups x 4 rows
    const int c0 = (tid & 31) * 4;        // l1/l2 cols
    const int c8 = (tid & 31) * 8;        // l3 cols

    {
        float acc[4][4];
#pragma unroll
        for (int i = 0; i < 4; ++i)
#pragma unroll
            for (int j = 0; j < 4; ++j) acc[i][j] = b1[c0 + j];
        tile44_fma(sF + r0 * 132, 132, w1 + c0, 128, 32, acc);
        for (int k = 128; k < 131; ++k) {
            float4 wv = *(const float4*)(w1 + (size_t)k * 128 + c0);
            float w_[4] = {wv.x, wv.y, wv.z, wv.w};
#pragma unroll
            for (int i = 0; i < 4; ++i) {
                float a = sF[(r0 + i) * 132 + k];
#pragma unroll
                for (int j = 0; j < 4; ++j) acc[i][j] = fmaf(a, w_[j], acc[i][j]);
            }
        }
#pragma unroll
        for (int i = 0; i < 4; ++i)
#pragma unroll
            for (int j = 0; j < 4; ++j)
                sH[(r0 + i) * 132 + c0 + j] = fmaxf(acc[i][j], 0.f);
    }
    __syncthreads();

    {
        float acc[4][4];
#pragma unroll
        for (int i = 0; i < 4; ++i)
#pragma unroll
            for (int j = 0; j < 4; ++j) acc[i][j] = b2[c0 + j];
        tile44_fma(sH + r0 * 132, 132, w2 + c0, 128, 32, acc);
#pragma unroll
        for (int i = 0; i < 4; ++i)
#pragma unroll
            for (int j = 0; j < 4; ++j)
                sF[(r0 + i) * 132 + c0 + j] = fmaxf(acc[i][j], 0.f);
    }
    __syncthreads();

    {
        float acc[4][8];
#pragma unroll
        for (int i = 0; i < 4; ++i)
#pragma unroll
            for (int j = 0; j < 8; ++j) acc[i][j] = 0.f;
        tile48_fma(sF + r0 * 132, 132, w3 + c8, 256, 32, acc);
        float pm[8];
#pragma unroll
        for (int j = 0; j < 8; ++j) pm[j] = -__builtin_inff();
#pragma unroll
        for (int i = 0; i < 4; ++i)
            if (r0 + i < valid)
#pragma unroll
                for (int j = 0; j < 8; ++j) pm[j] = fmaxf(pm[j], acc[i][j]);
#pragma unroll
        for (int j = 0; j < 8; ++j) sRed[(tid >> 5) * 256 + c8 + j] = pm[j];
    }
    __syncthreads();
    if (tid < 256) {
        float m = -__builtin_inff();
#pragma unroll
        for (int g = 0; g < 16; ++g) m = fmaxf(m, sRed[g * 256 + tid]);
        x2[(size_t)c * 256 + tid] = m + b3[tid];
    }
}

// ---------------------------------------------------------------------------
// gemm1f: A = cat([x2, pos2]) on the fly. K=259, relu.
// ---------------------------------------------------------------------------
__global__ __launch_bounds__(256) void gemm1f_kernel(const float* __restrict__ x2,
                                                     const float* __restrict__ pos2,
                                                     const float* __restrict__ W,
                                                     const float* __restrict__ bias,
                                                     float* __restrict__ C) {
    constexpr int K = 259, Nc = 256;
    __shared__ __align__(16) float sA[64 * 36];
    __shared__ __align__(16) float sB[32 * 68];
    const int tid = threadIdx.x;
    const int row0 = blockIdx.y * 64, col0 = blockIdx.x * 64;
    const int r0 = (tid >> 4) * 4, c0 = (tid & 15) * 4;
    float acc[4][4];
#pragma unroll
    for (int i = 0; i < 4; ++i)
#pragma unroll
        for (int j = 0; j < 4; ++j) acc[i][j] = 0.f;

    for (int kb = 0; kb < K; kb += 32) {
        for (int l = tid; l < 64 * 32; l += 256) {
            int r = l >> 5, k = l & 31;
            int gk = kb + k;
            float av = 0.f;
            if (gk < K) {
                int row = row0 + r;
                av = (gk < 256) ? x2[(size_t)row * 256 + gk]
                                : pos2[row * 3 + (gk - 256)];
            }
            sA[r * 36 + k] = av;
        }
        for (int l = tid; l < 32 * 64; l += 256) {
            int k = l >> 6, cc = l & 63;
            sB[k * 68 + cc] = (kb + k < K) ? W[(size_t)(kb + k) * Nc + col0 + cc] : 0.f;
        }
        __syncthreads();
        tile44_fma(sA + r0 * 36, 36, sB + c0, 68, 8, acc);
        __syncthreads();
    }
#pragma unroll
    for (int i = 0; i < 4; ++i)
#pragma unroll
        for (int j = 0; j < 4; ++j)
            C[(size_t)(row0 + r0 + i) * Nc + col0 + c0 + j] =
                fmaxf(acc[i][j] + bias[col0 + c0 + j], 0.f);
}

__global__ __launch_bounds__(256) void gemm_kernel(const float* __restrict__ A,
                                                   const float* __restrict__ W,
                                                   const float* __restrict__ bias,
                                                   float* __restrict__ C,
                                                   int M, int K, int Nc, int relu) {
    __shared__ __align__(16) float sA[64 * 36];
    __shared__ __align__(16) float sB[32 * 68];
    const int tid = threadIdx.x;
    const int row0 = blockIdx.y * 64, col0 = blockIdx.x * 64;
    const int r0 = (tid >> 4) * 4, c0 = (tid & 15) * 4;
    float acc[4][4];
#pragma unroll
    for (int i = 0; i < 4; ++i)
#pragma unroll
        for (int j = 0; j < 4; ++j) acc[i][j] = 0.f;

    for (int kb = 0; kb < K; kb += 32) {
        for (int l = tid; l < 64 * 32; l += 256) {
            int r = l >> 5, k = l & 31;
            sA[r * 36 + k] = (kb + k < K) ? A[(size_t)(row0 + r) * K + kb + k] : 0.f;
        }
        for (int l = tid; l < 32 * 64; l += 256) {
            int k = l >> 6, cc = l & 63;
            sB[k * 68 + cc] = (kb + k < K) ? W[(size_t)(kb + k) * Nc + col0 + cc] : 0.f;
        }
        __syncthreads();
        tile44_fma(sA + r0 * 36, 36, sB + c0, 68, 8, acc);
        __syncthreads();
    }
#pragma unroll
    for (int i = 0; i < 4; ++i)
#pragma unroll
        for (int j = 0; j < 4; ++j) {
            float v = acc[i][j] + bias[col0 + c0 + j];
            if (relu) v = fmaxf(v, 0.f);
            C[(size_t)(row0 + r0 + i) * Nc + col0 + c0 + j] = v;
        }
}

// ---------------------------------------------------------------------------
// maxpool over 512 rows + fc (1024->256), fused: one block per batch.
// ---------------------------------------------------------------------------
__global__ __launch_bounds__(1024) void mpfc_kernel(const float* __restrict__ h,
                                                    const float* __restrict__ w,
                                                    const float* __restrict__ bias,
                                                    float* __restrict__ out) {
    __shared__ float sG[1024];
    __shared__ float sP[4][256];
    const int b = blockIdx.x, tid = threadIdx.x;

    float m = -__builtin_inff();
    const float* hp = h + (size_t)b * 512 * 1024 + tid;
    for (int r = 0; r < 512; ++r) m = fmaxf(m, hp[(size_t)r * 1024]);
    sG[tid] = m;
    __syncthreads();

    const int c = tid & 255, kc = tid >> 8;
    float acc = 0.f;
    const float* wp = w + (size_t)(kc * 256) * 256 + c;
    const float* gp = sG + kc * 256;
    for (int k = 0; k < 256; ++k) acc = fmaf(gp[k], wp[(size_t)k * 256], acc);
    sP[kc][c] = acc;
    __syncthreads();
    if (tid < 256)
        out[b * 256 + tid] = ((sP[0][tid] + sP[1][tid]) + (sP[2][tid] + sP[3][tid]))
                             + bias[tid];
}

// ---------------------------------------------------------------------------
extern "C" void kernel_launch(void* const* d_in, const int* in_sizes, int n_in,
                              void* d_out, int out_size, void* d_ws, size_t ws_size,
                              hipStream_t stream) {
    const float* data  = (const float*)d_in[0];
    const float* s1w1  = (const float*)d_in[1];
    const float* s1b1  = (const float*)d_in[2];
    const float* s1w2  = (const float*)d_in[3];
    const float* s1b2  = (const float*)d_in[4];
    const float* s1w3  = (const float*)d_in[5];
    const float* s1b3  = (const float*)d_in[6];
    const float* s2w1  = (const float*)d_in[7];
    const float* s2b1  = (const float*)d_in[8];
    const float* s2w2  = (const float*)d_in[9];
    const float* s2b2  = (const float*)d_in[10];
    const float* s2w3  = (const float*)d_in[11];
    const float* s2b3  = (const float*)d_in[12];
    const float* s3w1  = (const float*)d_in[13];
    const float* s3b1  = (const float*)d_in[14];
    const float* s3w2  = (const float*)d_in[15];
    const float* s3b2  = (const float*)d_in[16];
    const float* s3w3  = (const float*)d_in[17];
    const float* s3b3  = (const float*)d_in[18];
    const float* fcw   = (const float*)d_in[19];
    const float* fcb   = (const float*)d_in[20];
    float* out = (float*)d_out;

    char* ws = (char*)d_ws;
    size_t o = 0;
    auto nxt = [&](size_t bytes) {
        size_t r = o;
        o += (bytes + 255) & ~(size_t)255;
        return r;
    };
    float* pos1 = (float*)(ws + nxt(4 * 2048 * 3 * 4));
    float* pos2 = (float*)(ws + nxt(4 * 512 * 3 * 4));
    float* mdG  = (float*)(ws + nxt(4 * 4096 * 4));
    int*   selG = (int*)(ws + nxt(4 * 2048 * 4));
    int*   nbr1 = (int*)(ws + nxt((size_t)8192 * 64 * 4));
    int*   cnt1 = (int*)(ws + nxt(8192 * 4));
    int*   nbr2 = (int*)(ws + nxt((size_t)2048 * 64 * 4));
    int*   cnt2 = (int*)(ws + nxt(2048 * 4));
    float* x1   = (float*)(ws + nxt((size_t)8192 * 128 * 4));
    float* x2   = (float*)(ws + nxt((size_t)2048 * 256 * 4));
    float* h1   = (float*)(ws + nxt((size_t)2048 * 256 * 4));
    float* h2   = (float*)(ws + nxt((size_t)2048 * 512 * 4));
    float* h3   = (float*)(ws + nxt((size_t)2048 * 1024 * 4));

    const float R1SQ = (float)(0.2 * 0.2);  // JAX weak-scalar f32 cast
    const float R2SQ = (float)(0.4 * 0.4);

    // k1: fps [1,512) alone
    fpsnbr_kernel<<<4, 512, 0, stream>>>(data, mdG, selG, pos1, 1, 512,
                                         R1SQ, nbr1, cnt1, 0,
                                         s1w1, s1b1, s1w2, s1b2, s1w3, s1b3, x1, 0);
    // k2: fps [512,1024) + nbr1 Q1
    fpsnbr_kernel<<<260, 512, 0, stream>>>(data, mdG, selG, pos1, 512, 1024,
                                           R1SQ, nbr1, cnt1, 0,
                                           s1w1, s1b1, s1w2, s1b2, s1w3, s1b3, x1, 0);
    // k3: fps [1024,1536) + nbr1 Q2 + mlp1 Q1
    fpsnbr_kernel<<<2308, 512, 0, stream>>>(data, mdG, selG, pos1, 1024, 1536,
                                            R1SQ, nbr1, cnt1, 512,
                                            s1w1, s1b1, s1w2, s1b2, s1w3, s1b3, x1, 0);
    // k4: fps [1536,2048) + nbr1 Q3 + mlp1 Q2
    fpsnbr_kernel<<<2308, 512, 0, stream>>>(data, mdG, selG, pos1, 1536, 2048,
                                            R1SQ, nbr1, cnt1, 1024,
                                            s1w1, s1b1, s1w2, s1b2, s1w3, s1b3, x1, 512);
    // k5: fps stage2 + nbr1 Q4 + mlp1 Q3
    fps2nbr_kernel<<<2308, 512, 0, stream>>>(data, pos1, pos2,
                                             R1SQ, nbr1, cnt1, 1536,
                                             s1w1, s1b1, s1w2, s1b2, s1w3, s1b3, x1, 1024);
    // k6: nbr2 + mlp1 Q4
    mlp1nbr2_kernel<<<2560, 256, 0, stream>>>(data, pos1, nbr1, cnt1,
                                              s1w1, s1b1, s1w2, s1b2,
                                              s1w3, s1b3, x1,
                                              pos1, pos2, R2SQ, nbr2, cnt2, 1536);
    mlp2_kernel<<<2048, 512, 0, stream>>>(x1, pos1, pos2, nbr2, cnt2,
                                          s2w1, s2b1, s2w2, s2b2, s2w3, s2b3, x2);
    gemm1f_kernel<<<dim3(4, 32), 256, 0, stream>>>(x2, pos2, s3w1, s3b1, h1);
    gemm_kernel<<<dim3(8, 32), 256, 0, stream>>>(h1, s3w2, s3b2, h2, 2048, 256, 512, 1);
    gemm_kernel<<<dim3(16, 32), 256, 0, stream>>>(h2, s3w3, s3b3, h3, 2048, 512, 1024, 0);
    mpfc_kernel<<<4, 1024, 0, stream>>>(h3, fcw, fcb, out);
}